// Round 10
// baseline (409.497 us; speedup 1.0000x reference)
//
#include <hip/hip_runtime.h>
#include <hip/hip_fp16.h>
#include <math.h>

// ---------------------------------------------------------------------------
// NatureCNN: conv×3 (implicit-im2col bf16 MFMA GEMMs, NHWC intermediates)
// | lin1+relu -> lin2 (bf16 MFMA) -> concat feat -> wih0 pre-act GEMMs (fp32)
// -> 2×(2-layer LSTM) -> fused head.
// Round 10: LSTM restructured to ONE barrier per step. Thread (j,ks) owns all
// 4 gates of h-element j over a 8-way k-split (28 packed-f16-pair weight regs);
// 3-level shfl_xor butterfly completes the dots; lane ks==0 does activations,
// keeps c[j] in a REGISTER, writes h[j] to a double-buffered LDS h (read t&1,
// write (t+1)&1 -> no read/write race, single barrier). Gates array and
// combiner phase eliminated.
// ---------------------------------------------------------------------------

typedef __attribute__((ext_vector_type(4))) float f32x4;
typedef __attribute__((ext_vector_type(8))) short s16x8;
typedef __attribute__((ext_vector_type(8))) unsigned short u16x8;

__device__ __forceinline__ unsigned short f2bf(float f){
  union { float f; unsigned int u; } v; v.f = f;
  unsigned int r = (v.u + 0x7fffu + ((v.u >> 16) & 1u)) >> 16;
  return (unsigned short)r;
}
__device__ __forceinline__ unsigned short f2h(float f){
  return __half_as_ushort(__float2half(f));
}
__device__ __forceinline__ float sigmoidf_(float x){ return 1.0f/(1.0f+__expf(-x)); }
__device__ __forceinline__ float tanhf_(float x){
  float e = __expf(-2.0f*fabsf(x));
  float t = (1.0f - e)/(1.0f + e);
  return copysignf(t, x);
}

#if __has_builtin(__builtin_amdgcn_fdot2)
typedef _Float16 f16x2 __attribute__((ext_vector_type(2)));
__device__ __forceinline__ float dot2h(unsigned int a, unsigned int b, float c){
  union { unsigned int u; f16x2 h; } ua, ub;
  ua.u = a; ub.u = b;
  return __builtin_amdgcn_fdot2(ua.h, ub.h, c, false);
}
#else
__device__ __forceinline__ float dot2h(unsigned int a, unsigned int b, float c){
  __half2 ha = *(__half2*)&a, hb = *(__half2*)&b;
  float2 fa = __half22float2(ha), fb = __half22float2(hb);
  return c + fa.x*fb.x + fa.y*fb.y;
}
#endif

// ---------------------------------------------------------------------------
// ONE merged prep kernel. blockIdx.y selects the job; grid-stride within job.
//  0: data cast-pad    1: l1w cast-pad    2: l2w cast    3: c1w cast
//  4: c2w reorder      5: c3w reorder     6/7: wihS/R permute
//  8: six recurrent mats -> per-thread f16-pair frags:
//     wpk[mat*22400 + ((q*100+j)*8+ks)*7+p] = pack(W[q*100+j][2*(ks*7+p)],
//                                                  W[q*100+j][2*(ks*7+p)+1])
//     zero for pair index >= 50.
// ---------------------------------------------------------------------------
__global__ void prep_k(
    const float* __restrict__ data, unsigned short* __restrict__ data_bf,
    const float* __restrict__ l1w,  unsigned short* __restrict__ l1w_bf,
    const float* __restrict__ l2w,  unsigned short* __restrict__ l2w_bf,
    const float* __restrict__ c1w,  unsigned short* __restrict__ c1w_bf,
    const float* __restrict__ c2w,  unsigned short* __restrict__ c2w_bf,
    const float* __restrict__ c3w,  unsigned short* __restrict__ c3w_bf,
    const float* __restrict__ wihS, unsigned short* __restrict__ wihS_bf,
    const float* __restrict__ wihR, unsigned short* __restrict__ wihR_bf,
    const float* __restrict__ m0, const float* __restrict__ m1,
    const float* __restrict__ m2, const float* __restrict__ m3,
    const float* __restrict__ m4, const float* __restrict__ m5,
    unsigned int* __restrict__ wpk)
{
  const int job = blockIdx.y;
  const int stride = gridDim.x * blockDim.x;
  int e0 = blockIdx.x * blockDim.x + threadIdx.x;
  if (job == 0){
    for (int e = e0; e < 2048*1536; e += stride){
      int r = e / 1536, k = e - r*1536;
      data_bf[e] = (k < 1500) ? f2bf(data[(size_t)r*1500 + k]) : (unsigned short)0;
    }
  } else if (job == 1){
    for (int e = e0; e < 1024*1536; e += stride){
      int r = e / 1536, k = e - r*1536;
      l1w_bf[e] = (k < 1500) ? f2bf(l1w[(size_t)r*1500 + k]) : (unsigned short)0;
    }
  } else if (job == 2){
    for (int e = e0; e < 512*1024; e += stride) l2w_bf[e] = f2bf(l2w[e]);
  } else if (job == 3){
    for (int e = e0; e < 32*192; e += stride) c1w_bf[e] = f2bf(c1w[e]);
  } else if (job == 4){
    for (int e = e0; e < 64*512; e += stride){
      int oc = e >> 9, r = e & 511;
      int tap = r >> 5, ic = r & 31;
      c2w_bf[e] = f2bf(c2w[(size_t)oc*512 + ic*16 + tap]);
    }
  } else if (job == 5){
    for (int e = e0; e < 64*576; e += stride){
      int oc = e / 576, r = e - oc*576;
      int tap = r >> 6, ic = r & 63;
      c3w_bf[e] = f2bf(c3w[(size_t)oc*576 + ic*9 + tap]);
    }
  } else if (job == 6 || job == 7){
    const float* src = (job == 6) ? wihS : wihR;
    unsigned short* dst = (job == 6) ? wihS_bf : wihR_bf;
    for (int e = e0; e < 400*1536; e += stride){
      int g = e / 1536, k = e - g*1536;
      int ksrc = (k < 1024) ? ((k & 63)*16 + (k >> 6)) : k;
      dst[e] = f2bf(src[(size_t)g*1536 + ksrc]);
    }
  } else {
    const float* srcs[6] = {m0,m1,m2,m3,m4,m5};
    for (int e = e0; e < 6*22400; e += stride){
      int mat = e / 22400, r = e - mat*22400;
      int p = r % 7, rr = r / 7;
      int ks = rr & 7, g = rr >> 3;       // g = q*100+j in [0,400)
      int pk = ks*7 + p;
      unsigned int v = 0u;
      if (pk < 50){
        const float* src = srcs[mat];
        unsigned int lo = f2h(src[g*100 + 2*pk]);
        unsigned int hi = f2h(src[g*100 + 2*pk + 1]);
        v = lo | (hi << 16);
      }
      wpk[e] = v;
    }
  }
}

// ---------------------------------------------------------------------------
// bf16 MFMA GEMM (unchanged, passing since round 2)
// ---------------------------------------------------------------------------
template<int BM,int BN,int WAVES_M,int WAVES_N,int AMODE,int CMODE,int RELU,int NGUARD,
         int CIN,int HI,int WI,int KH,int KW,int ST,int HO,int WO>
__global__ __launch_bounds__(256) void mgemm(
    const void* __restrict__ Av, const unsigned short* __restrict__ B,
    void* __restrict__ Cv, const float* __restrict__ bias,
    int M, int N, int K, int lda, int ldc, int cstride)
{
  constexpr int BK = 64;
  constexpr int WROWS = BM / WAVES_M;
  constexpr int WCOLS = BN / WAVES_N;
  constexpr int MF = WROWS / 16;
  constexpr int NF = WCOLS / 16;
  constexpr int HOWO = HO*WO;
  __shared__ unsigned short As[BM*BK];
  __shared__ unsigned short Bs[BN*BK];
  const int tid = threadIdx.x;
  const int bm = blockIdx.x * BM;
  const int bn = blockIdx.y * BN;
  const int lane = tid & 63, w = tid >> 6;
  const int wm = w / WAVES_N, wn = w % WAVES_N;
  const int m0 = wm * WROWS, n0 = wn * WCOLS;

  f32x4 acc[MF][NF] = {};

  const int ar = tid >> 1;
  const int as0 = 4 * (tid & 1);
  const int row_g = bm + ar;
  int a_n = 0, a_oy = 0, a_ox = 0;
  if (AMODE != 0){ a_n = row_g / HOWO; int p = row_g - a_n*HOWO; a_oy = p / WO; a_ox = p - a_oy*WO; }

  for (int kt = 0; kt < K; kt += BK){
    #pragma unroll
    for (int si = 0; si < 4; ++si){
      int s = as0 + si;
      int k0 = kt + s*8;
      u16x8 val;
      if constexpr (AMODE == 0){
        val = *(const u16x8*)((const unsigned short*)Av + (size_t)row_g*lda + k0);
      } else if constexpr (AMODE == 1){
        int ic = k0 >> 6, r = k0 & 63, ky = r >> 3;
        const float* src = (const float*)Av +
            (((size_t)(a_n*CIN + ic)*HI + a_oy*ST + ky)*WI + a_ox*ST);
        f32x4 f0 = *(const f32x4*)src;
        f32x4 f1 = *(const f32x4*)(src + 4);
        val[0]=f2bf(f0[0]); val[1]=f2bf(f0[1]); val[2]=f2bf(f0[2]); val[3]=f2bf(f0[3]);
        val[4]=f2bf(f1[0]); val[5]=f2bf(f1[1]); val[6]=f2bf(f1[2]); val[7]=f2bf(f1[3]);
      } else {
        int tap = k0 / CIN, ic0 = k0 - tap*CIN;
        int ky = tap / KW, kx = tap - ky*KW;
        const unsigned short* src = (const unsigned short*)Av +
            (((size_t)(a_n*HI + a_oy*ST + ky)*WI + a_ox*ST + kx)*CIN + ic0);
        val = *(const u16x8*)src;
      }
      int phys = s ^ ((ar >> 1) & 7);
      *(u16x8*)&As[ar*BK + phys*8] = val;
    }
    if constexpr (BN == 64){
      int br = tid >> 2, bs0 = 2*(tid & 3);
      #pragma unroll
      for (int si = 0; si < 2; ++si){
        int s = bs0 + si, k0 = kt + s*8;
        int n_g = bn + br;
        u16x8 val = {};
        if (!NGUARD || n_g < N) val = *(const u16x8*)(B + (size_t)n_g*K + k0);
        int phys = s ^ ((br >> 1) & 7);
        *(u16x8*)&Bs[br*BK + phys*8] = val;
      }
    } else {
      int br = tid >> 3, s = tid & 7, k0 = kt + s*8;
      int n_g = bn + br;
      u16x8 val = {};
      if (!NGUARD || n_g < N) val = *(const u16x8*)(B + (size_t)n_g*K + k0);
      int phys = s ^ ((br >> 1) & 7);
      *(u16x8*)&Bs[br*BK + phys*8] = val;
    }
    __syncthreads();
    #pragma unroll
    for (int ks = 0; ks < 2; ++ks){
      s16x8 a[MF], b[NF];
      #pragma unroll
      for (int i = 0; i < MF; ++i){
        int row = m0 + i*16 + (lane & 15);
        int phys = (ks*4 + (lane >> 4)) ^ ((row >> 1) & 7);
        a[i] = *(const s16x8*)&As[row*BK + phys*8];
      }
      #pragma unroll
      for (int j = 0; j < NF; ++j){
        int row = n0 + j*16 + (lane & 15);
        int phys = (ks*4 + (lane >> 4)) ^ ((row >> 1) & 7);
        b[j] = *(const s16x8*)&Bs[row*BK + phys*8];
      }
      #pragma unroll
      for (int i = 0; i < MF; ++i)
        #pragma unroll
        for (int j = 0; j < NF; ++j)
          acc[i][j] = __builtin_amdgcn_mfma_f32_16x16x32_bf16(a[i], b[j], acc[i][j], 0, 0, 0);
    }
    __syncthreads();
  }

  if constexpr (CMODE == 3){
    float* Cf = (float*)Cv;
    #pragma unroll
    for (int i = 0; i < MF; ++i)
      #pragma unroll
      for (int j = 0; j < NF; ++j){
        int col = bn + n0 + j*16 + (lane & 15);
        float bv = (bias && (!NGUARD || col < N)) ? bias[col] : 0.f;
        #pragma unroll
        for (int q = 0; q < 4; ++q){
          int row = bm + m0 + i*16 + (lane >> 4)*4 + q;
          float v = acc[i][j][q] + bv;
          if (RELU) v = fmaxf(v, 0.f);
          if (!NGUARD || col < N) Cf[(size_t)row*ldc + col] = v;
        }
      }
  } else {
    unsigned short* tile = As;
    #pragma unroll
    for (int i = 0; i < MF; ++i)
      #pragma unroll
      for (int j = 0; j < NF; ++j){
        int col = n0 + j*16 + (lane & 15);
        float bv = bias ? bias[bn + col] : 0.f;
        #pragma unroll
        for (int q = 0; q < 4; ++q){
          int row = m0 + i*16 + (lane >> 4)*4 + q;
          float v = acc[i][j][q] + bv;
          if (RELU) v = fmaxf(v, 0.f);
          tile[row*BN + col] = f2bf(v);
        }
      }
    __syncthreads();
    unsigned short* Cu = (unsigned short*)Cv;
    constexpr int CHUNKS = (BM*BN)/(256*8);
    #pragma unroll
    for (int c = 0; c < CHUNKS; ++c){
      int flat = tid*8 + c*2048;
      int row = flat / BN, col = flat - (flat/BN)*BN;
      u16x8 v = *(const u16x8*)&tile[flat];
      int rg = bm + row;
      size_t addr;
      if constexpr (CMODE == 0) addr = (size_t)rg*ldc + bn + col;
      else { int n = rg >> 4, p = rg & 15; addr = (size_t)n*cstride + p*64 + col; }
      *(u16x8*)&Cu[addr] = v;
    }
  }
}

// ---------------------------------------------------------------------------
// LSTM: one block per segment; both stacks. 832 threads (800 active).
// Thread (j,ks): j=tid>>3 (h element), ks=tid&7 (8-way k-split over 56 padded
// f16 pairs, 7 per thread). Each thread computes partials of ALL 4 gates of
// element j (28 weight u32 regs). 3-level shfl_xor butterfly -> lane ks==0
// holds full pre-acts, applies activations, updates register c[j], writes
// h[j] into the OTHER h buffer (double-buffered) -> 1 barrier per step.
// L1 x-part batched (no barriers). Head fused.
// ---------------------------------------------------------------------------
__global__ __launch_bounds__(832,4) void lstm_k(
    const float* __restrict__ X0s, const float* __restrict__ X0r,
    const unsigned int* __restrict__ wpk,  // 6 mats x 22400 u32 per-thread frags
    const float* __restrict__ s_bih0, const float* __restrict__ s_bhh0,
    const float* __restrict__ s_bih1, const float* __restrict__ s_bhh1,
    const float* __restrict__ r_bih0, const float* __restrict__ r_bhh0,
    const float* __restrict__ r_bih1, const float* __restrict__ r_bhh1,
    const float* __restrict__ f1w, const float* __restrict__ f1b,
    const float* __restrict__ f2w, const float* __restrict__ f2b,
    float* __restrict__ out)
{
  __shared__ alignas(16) unsigned int h0p[2][64];   // dbuf, 56 pairs (+pad)
  __shared__ alignas(16) unsigned int h1p[2][64];
  __shared__ alignas(16) unsigned int hbufp[1792];  // 32 steps x 56 pairs
  __shared__ alignas(16) float Xl1[12800];          // layer-1 x-part, 32 x 400
  __shared__ float xin[208];                        // head input [outR|outS]
  __shared__ float mid[512];                        // head hidden

  const int b = blockIdx.x, tid = threadIdx.x;
  const int j = tid >> 3, ks = tid & 7;
  const bool act = (tid < 800);                 // j < 100
  const bool lead = act && (ks == 0);
  const int pb = ks * 7;                        // pair base in h rows

  if (tid < 128){ h0p[0][tid & 63] = 0u; h1p[0][tid & 63] = 0u; }
  else if (tid < 256){ h0p[1][tid & 63] = 0u; h1p[1][tid & 63] = 0u; }
  for (int e = tid; e < 1792; e += 832) hbufp[e] = 0u;
  float c0r = 0.f, c1r = 0.f;
  __syncthreads();

  #pragma unroll 1
  for (int s = 0; s < 2; ++s){
    const float* Xp = (s ? X0r : X0s) + (size_t)b*32*400;
    const unsigned int* w0P  = wpk + (size_t)(s ? 3 : 0)*22400;
    const unsigned int* w1xP = wpk + (size_t)(s ? 4 : 1)*22400;
    const unsigned int* w1hP = wpk + (size_t)(s ? 5 : 2)*22400;
    const float* bi0 = s ? r_bih0 : s_bih0;
    const float* bh0 = s ? r_bhh0 : s_bhh0;
    const float* bi1 = s ? r_bih1 : s_bih1;
    const float* bh1 = s ? r_bhh1 : s_bhh1;

    // ------------- layer 0 (recurrent; 1 barrier/step) -------------
    {
      unsigned int wr[4][7];
      float bs[4], xc[4] = {0,0,0,0}, xn[4];
      if (act){
        #pragma unroll
        for (int q = 0; q < 4; ++q)
          #pragma unroll
          for (int p = 0; p < 7; ++p)
            wr[q][p] = w0P[(((q*100 + j)*8) + ks)*7 + p];
      }
      if (lead){
        #pragma unroll
        for (int q = 0; q < 4; ++q){
          bs[q] = bi0[q*100 + j] + bh0[q*100 + j];
          xc[q] = Xp[q*100 + j];
        }
      }
      #pragma unroll 1
      for (int t = 0; t < 32; ++t){
        if (lead && t < 31){
          #pragma unroll
          for (int q = 0; q < 4; ++q) xn[q] = Xp[(t+1)*400 + q*100 + j];
        }
        if (act){
          const unsigned int* hb = h0p[t & 1];
          float pr[4];
          #pragma unroll
          for (int q = 0; q < 4; ++q){
            float a = 0.f;
            #pragma unroll
            for (int p = 0; p < 7; ++p) a = dot2h(wr[q][p], hb[pb + p], a);
            pr[q] = a;
          }
          #pragma unroll
          for (int m = 1; m < 8; m <<= 1){
            #pragma unroll
            for (int q = 0; q < 4; ++q) pr[q] += __shfl_xor(pr[q], m);
          }
          if (lead){
            float iv = sigmoidf_(pr[0] + xc[0] + bs[0]);
            float fv = sigmoidf_(pr[1] + xc[1] + bs[1]);
            float gv = tanhf_  (pr[2] + xc[2] + bs[2]);
            float ov = sigmoidf_(pr[3] + xc[3] + bs[3]);
            c0r = fv*c0r + iv*gv;
            float hn = ov*tanhf_(c0r);
            unsigned short hv = f2h(hn);
            ((unsigned short*)h0p[(t+1) & 1])[j] = hv;
            ((unsigned short*)hbufp)[t*112 + j] = hv;
            #pragma unroll
            for (int q = 0; q < 4; ++q) xc[q] = xn[q];
          }
        }
        __syncthreads();
      }
    }
    // ------------- layer 1a: x-part pre-acts (batch, no barriers) -------------
    {
      unsigned int wx[4][7];
      float bs1[4];
      if (act){
        #pragma unroll
        for (int q = 0; q < 4; ++q)
          #pragma unroll
          for (int p = 0; p < 7; ++p)
            wx[q][p] = w1xP[(((q*100 + j)*8) + ks)*7 + p];
      }
      if (lead){
        #pragma unroll
        for (int q = 0; q < 4; ++q) bs1[q] = bi1[q*100 + j] + bh1[q*100 + j];
      }
      #pragma unroll 1
      for (int t = 0; t < 32; ++t){
        if (act){
          const unsigned int* xb = hbufp + t*56;
          float pr[4];
          #pragma unroll
          for (int q = 0; q < 4; ++q){
            float a = 0.f;
            #pragma unroll
            for (int p = 0; p < 7; ++p) a = dot2h(wx[q][p], xb[pb + p], a);
            pr[q] = a;
          }
          #pragma unroll
          for (int m = 1; m < 8; m <<= 1){
            #pragma unroll
            for (int q = 0; q < 4; ++q) pr[q] += __shfl_xor(pr[q], m);
          }
          if (lead){
            #pragma unroll
            for (int q = 0; q < 4; ++q) Xl1[t*400 + q*100 + j] = pr[q] + bs1[q];
          }
        }
      }
      __syncthreads();
    }
    // ------------- layer 1b: recurrent (1 barrier/step) -------------
    {
      unsigned int wh[4][7];
      if (act){
        #pragma unroll
        for (int q = 0; q < 4; ++q)
          #pragma unroll
          for (int p = 0; p < 7; ++p)
            wh[q][p] = w1hP[(((q*100 + j)*8) + ks)*7 + p];
      }
      #pragma unroll 1
      for (int t = 0; t < 32; ++t){
        if (act){
          const unsigned int* hb = h1p[t & 1];
          float pr[4];
          #pragma unroll
          for (int q = 0; q < 4; ++q){
            float a = 0.f;
            #pragma unroll
            for (int p = 0; p < 7; ++p) a = dot2h(wh[q][p], hb[pb + p], a);
            pr[q] = a;
          }
          #pragma unroll
          for (int m = 1; m < 8; m <<= 1){
            #pragma unroll
            for (int q = 0; q < 4; ++q) pr[q] += __shfl_xor(pr[q], m);
          }
          if (lead){
            float iv = sigmoidf_(pr[0] + Xl1[t*400 + j]);
            float fv = sigmoidf_(pr[1] + Xl1[t*400 + 100 + j]);
            float gv = tanhf_  (pr[2] + Xl1[t*400 + 200 + j]);
            float ov = sigmoidf_(pr[3] + Xl1[t*400 + 300 + j]);
            c1r = fv*c1r + iv*gv;
            float hn = ov*tanhf_(c1r);
            ((unsigned short*)h1p[(t+1) & 1])[j] = f2h(hn);
            if (t == 31){
              if (s) xin[j] = hn;          // outR -> head cols [0,100)
              else   xin[100 + j] = hn;    // outS -> head cols [100,200)
            }
          }
        }
        __syncthreads();
      }
    }
  }

  // ------------- fused head: out[b] = relu(xin@f1w^T+b1)@f2w^T+b2 -------------
  if (tid < 512){
    float acc = f1b[tid];
    const float* wrow = f1w + (size_t)tid*200;
    #pragma unroll 4
    for (int k = 0; k < 200; ++k) acc += xin[k]*wrow[k];
    mid[tid] = fmaxf(acc, 0.f);
  }
  __syncthreads();
  if (tid < 130){
    float acc = f2b[tid];
    const float* wrow = f2w + (size_t)tid*512;
    #pragma unroll 4
    for (int k = 0; k < 512; ++k) acc += mid[k]*wrow[k];
    out[b*130 + tid] = acc;
  }
}

extern "C" void kernel_launch(void* const* d_in, const int* in_sizes, int n_in,
                              void* d_out, int out_size, void* d_ws, size_t ws_size,
                              hipStream_t stream)
{
  const float* obs  = (const float*)d_in[0];
  const float* data = (const float*)d_in[1];
  const float* c1w = (const float*)d_in[2];  const float* c1b = (const float*)d_in[3];
  const float* c2w = (const float*)d_in[4];  const float* c2b = (const float*)d_in[5];
  const float* c3w = (const float*)d_in[6];  const float* c3b = (const float*)d_in[7];
  const float* l1w = (const float*)d_in[8];  const float* l1b = (const float*)d_in[9];
  const float* l2w = (const float*)d_in[10]; const float* l2b = (const float*)d_in[11];
  const float* s_wih0=(const float*)d_in[12]; const float* s_whh0=(const float*)d_in[13];
  const float* s_bih0=(const float*)d_in[14]; const float* s_bhh0=(const float*)d_in[15];
  const float* s_wih1=(const float*)d_in[16]; const float* s_whh1=(const float*)d_in[17];
  const float* s_bih1=(const float*)d_in[18]; const float* s_bhh1=(const float*)d_in[19];
  const float* r_wih0=(const float*)d_in[20]; const float* r_whh0=(const float*)d_in[21];
  const float* r_bih0=(const float*)d_in[22]; const float* r_bhh0=(const float*)d_in[23];
  const float* r_wih1=(const float*)d_in[24]; const float* r_whh1=(const float*)d_in[25];
  const float* r_bih1=(const float*)d_in[26]; const float* r_bhh1=(const float*)d_in[27];
  const float* f1w=(const float*)d_in[28]; const float* f1b=(const float*)d_in[29];
  const float* f2w=(const float*)d_in[30]; const float* f2b=(const float*)d_in[31];
  float* out = (float*)d_out;
  (void)in_sizes; (void)n_in; (void)out_size;

  // ---- workspace layout (bytes, 256-aligned); total ~ 67 MB ----
  char* p = (char*)d_ws;
  auto alloc = [&](size_t bytes){ void* r = (void*)p; p += (bytes + 255) & ~(size_t)255; return r; };
  unsigned short* data_bf = (unsigned short*)alloc((size_t)2048*1536*2);
  unsigned short* c1w_bf  = (unsigned short*)alloc((size_t)32*192*2);
  unsigned short* c2w_bf  = (unsigned short*)alloc((size_t)64*512*2);
  unsigned short* c3w_bf  = (unsigned short*)alloc((size_t)64*576*2);
  unsigned short* l1w_bf  = (unsigned short*)alloc((size_t)1024*1536*2);
  unsigned short* l2w_bf  = (unsigned short*)alloc((size_t)512*1024*2);
  unsigned short* wihS_bf = (unsigned short*)alloc((size_t)400*1536*2);
  unsigned short* wihR_bf = (unsigned short*)alloc((size_t)400*1536*2);
  unsigned short* conv1o  = (unsigned short*)alloc((size_t)2048*225*32*2);  // NHWC
  unsigned short* conv2o  = (unsigned short*)alloc((size_t)2048*36*64*2);   // NHWC
  unsigned short* feat    = (unsigned short*)alloc((size_t)2048*1536*2);
  unsigned short* lin1o   = (unsigned short*)alloc((size_t)2048*1024*2);
  float* X0s  = (float*)alloc((size_t)1024*400*4);
  float* X0r  = (float*)alloc((size_t)1024*400*4);
  unsigned int* wpk = (unsigned int*)alloc((size_t)6*22400*4);
  (void)ws_size;

  // ---- merged prep (1 launch) ----
  prep_k<<<dim3(512,9),256,0,stream>>>(
      data, data_bf, l1w, l1w_bf, l2w, l2w_bf, c1w, c1w_bf,
      c2w, c2w_bf, c3w, c3w_bf, s_wih0, wihS_bf, r_wih0, wihR_bf,
      s_whh0, s_wih1, s_whh1, r_whh0, r_wih1, r_whh1, wpk);

  // ---- GEMM chain (bf16 MFMA, fp32 accumulate) ----
  mgemm<128,32,4,1, 1,0,1,0, 3,64,64,8,8,4,15,15><<<dim3(3600,1),256,0,stream>>>(
      obs, c1w_bf, conv1o, c1b, 460800, 32, 192, 0, 32, 0);
  mgemm<128,64,2,2, 2,0,1,0, 32,15,15,4,4,2,6,6><<<dim3(576,1),256,0,stream>>>(
      conv1o, c2w_bf, conv2o, c2b, 73728, 64, 512, 0, 64, 0);
  mgemm<128,64,2,2, 0,0,1,0, 1,1,1,1,1,1,1,1><<<dim3(16,16),256,0,stream>>>(
      data_bf, l1w_bf, lin1o, l1b, 2048, 1024, 1536, 1536, 1024, 0);
  mgemm<128,64,2,2, 2,2,1,0, 64,6,6,3,3,1,4,4><<<dim3(256,1),256,0,stream>>>(
      conv2o, c3w_bf, feat, c3b, 32768, 64, 576, 0, 0, 1536);
  mgemm<128,64,2,2, 0,0,0,0, 1,1,1,1,1,1,1,1><<<dim3(16,8),256,0,stream>>>(
      lin1o, l2w_bf, feat + 1024, l2b, 2048, 512, 1024, 1024, 1536, 0);
  mgemm<128,64,2,2, 0,3,0,1, 1,1,1,1,1,1,1,1><<<dim3(8,7),256,0,stream>>>(
      feat, wihS_bf, X0s, (const float*)nullptr, 1024, 400, 1536, 1536, 400, 0);
  mgemm<128,64,2,2, 0,3,0,1, 1,1,1,1,1,1,1,1><<<dim3(8,7),256,0,stream>>>(
      feat + (size_t)1024*1536, wihR_bf, X0r, (const float*)nullptr, 1024, 400, 1536, 1536, 400, 0);

  // ---- sequential LSTM + fused head ----
  lstm_k<<<32,832,0,stream>>>(X0s, X0r, wpk,
                              s_bih0,s_bhh0,s_bih1,s_bhh1,
                              r_bih0,r_bhh0,r_bih1,r_bhh1,
                              f1w, f1b, f2w, f2b, out);
}

// Round 11
// 331.627 us; speedup vs baseline: 1.2348x; 1.2348x over previous
//
#include <hip/hip_runtime.h>
#include <hip/hip_fp16.h>
#include <math.h>

// ---------------------------------------------------------------------------
// NatureCNN: conv×3 (implicit-im2col bf16 MFMA GEMMs, NHWC intermediates)
// | lin1+relu -> lin2 (bf16 MFMA) -> concat feat -> wih0 pre-act GEMMs (fp32)
// -> 2×(2-layer LSTM) -> fused head.
// Round 11: LSTM rebuilt around the measured limiter (LDS pipe saturated by
// per-wave broadcast re-reads of h: 13 waves x 25 reads ~ 1900cyc/step).
// Now 4 waves (256 thr): thread (e,sub) owns 2 FULL gate rows in registers
// (sub0: i,g; sub1: f,o), h read as 13 broadcast ds_read_b128 per wave
// (~620cyc/step total), one shfl_xor hands i*g to sub1 which holds c in a
// register; h double-buffered -> 1 barrier/step.
// ---------------------------------------------------------------------------

typedef __attribute__((ext_vector_type(4))) float f32x4;
typedef __attribute__((ext_vector_type(8))) short s16x8;
typedef __attribute__((ext_vector_type(8))) unsigned short u16x8;
typedef __attribute__((ext_vector_type(4))) unsigned int u32x4;

__device__ __forceinline__ unsigned short f2bf(float f){
  union { float f; unsigned int u; } v; v.f = f;
  unsigned int r = (v.u + 0x7fffu + ((v.u >> 16) & 1u)) >> 16;
  return (unsigned short)r;
}
__device__ __forceinline__ unsigned short f2h(float f){
  return __half_as_ushort(__float2half(f));
}
__device__ __forceinline__ float sigmoidf_(float x){ return 1.0f/(1.0f+__expf(-x)); }
__device__ __forceinline__ float tanhf_(float x){
  float e = __expf(-2.0f*fabsf(x));
  float t = (1.0f - e)/(1.0f + e);
  return copysignf(t, x);
}

#if __has_builtin(__builtin_amdgcn_fdot2)
typedef _Float16 f16x2 __attribute__((ext_vector_type(2)));
__device__ __forceinline__ float dot2h(unsigned int a, unsigned int b, float c){
  union { unsigned int u; f16x2 h; } ua, ub;
  ua.u = a; ub.u = b;
  return __builtin_amdgcn_fdot2(ua.h, ub.h, c, false);
}
#else
__device__ __forceinline__ float dot2h(unsigned int a, unsigned int b, float c){
  __half2 ha = *(__half2*)&a, hb = *(__half2*)&b;
  float2 fa = __half22float2(ha), fb = __half22float2(hb);
  return c + fa.x*fb.x + fa.y*fb.y;
}
#endif

// ---------------------------------------------------------------------------
// ONE merged prep kernel. blockIdx.y selects the job; grid-stride within job.
//  0: data cast-pad    1: l1w cast-pad    2: l2w cast    3: c1w cast
//  4: c2w reorder      5: c3w reorder     6/7: wihS/R permute
//  8: six recurrent mats -> f16-pair-packed [50][400] u32 each:
//     wpk[mat*20000 + kk*400 + g] = pack(W[g][2kk], W[g][2kk+1])
// ---------------------------------------------------------------------------
__global__ void prep_k(
    const float* __restrict__ data, unsigned short* __restrict__ data_bf,
    const float* __restrict__ l1w,  unsigned short* __restrict__ l1w_bf,
    const float* __restrict__ l2w,  unsigned short* __restrict__ l2w_bf,
    const float* __restrict__ c1w,  unsigned short* __restrict__ c1w_bf,
    const float* __restrict__ c2w,  unsigned short* __restrict__ c2w_bf,
    const float* __restrict__ c3w,  unsigned short* __restrict__ c3w_bf,
    const float* __restrict__ wihS, unsigned short* __restrict__ wihS_bf,
    const float* __restrict__ wihR, unsigned short* __restrict__ wihR_bf,
    const float* __restrict__ m0, const float* __restrict__ m1,
    const float* __restrict__ m2, const float* __restrict__ m3,
    const float* __restrict__ m4, const float* __restrict__ m5,
    unsigned int* __restrict__ wpk)
{
  const int job = blockIdx.y;
  const int stride = gridDim.x * blockDim.x;
  int e0 = blockIdx.x * blockDim.x + threadIdx.x;
  if (job == 0){
    for (int e = e0; e < 2048*1536; e += stride){
      int r = e / 1536, k = e - r*1536;
      data_bf[e] = (k < 1500) ? f2bf(data[(size_t)r*1500 + k]) : (unsigned short)0;
    }
  } else if (job == 1){
    for (int e = e0; e < 1024*1536; e += stride){
      int r = e / 1536, k = e - r*1536;
      l1w_bf[e] = (k < 1500) ? f2bf(l1w[(size_t)r*1500 + k]) : (unsigned short)0;
    }
  } else if (job == 2){
    for (int e = e0; e < 512*1024; e += stride) l2w_bf[e] = f2bf(l2w[e]);
  } else if (job == 3){
    for (int e = e0; e < 32*192; e += stride) c1w_bf[e] = f2bf(c1w[e]);
  } else if (job == 4){
    for (int e = e0; e < 64*512; e += stride){
      int oc = e >> 9, r = e & 511;
      int tap = r >> 5, ic = r & 31;
      c2w_bf[e] = f2bf(c2w[(size_t)oc*512 + ic*16 + tap]);
    }
  } else if (job == 5){
    for (int e = e0; e < 64*576; e += stride){
      int oc = e / 576, r = e - oc*576;
      int tap = r >> 6, ic = r & 63;
      c3w_bf[e] = f2bf(c3w[(size_t)oc*576 + ic*9 + tap]);
    }
  } else if (job == 6 || job == 7){
    const float* src = (job == 6) ? wihS : wihR;
    unsigned short* dst = (job == 6) ? wihS_bf : wihR_bf;
    for (int e = e0; e < 400*1536; e += stride){
      int g = e / 1536, k = e - g*1536;
      int ksrc = (k < 1024) ? ((k & 63)*16 + (k >> 6)) : k;
      dst[e] = f2bf(src[(size_t)g*1536 + ksrc]);
    }
  } else {
    const float* srcs[6] = {m0,m1,m2,m3,m4,m5};
    for (int e = e0; e < 6*20000; e += stride){
      int mat = e / 20000, r = e - mat*20000;
      int kk = r / 400, g = r - kk*400;
      const float* src = srcs[mat];
      unsigned int lo = f2h(src[g*100 + 2*kk]);
      unsigned int hi = f2h(src[g*100 + 2*kk + 1]);
      wpk[e] = lo | (hi << 16);
    }
  }
}

// ---------------------------------------------------------------------------
// bf16 MFMA GEMM (unchanged, passing since round 2)
// ---------------------------------------------------------------------------
template<int BM,int BN,int WAVES_M,int WAVES_N,int AMODE,int CMODE,int RELU,int NGUARD,
         int CIN,int HI,int WI,int KH,int KW,int ST,int HO,int WO>
__global__ __launch_bounds__(256) void mgemm(
    const void* __restrict__ Av, const unsigned short* __restrict__ B,
    void* __restrict__ Cv, const float* __restrict__ bias,
    int M, int N, int K, int lda, int ldc, int cstride)
{
  constexpr int BK = 64;
  constexpr int WROWS = BM / WAVES_M;
  constexpr int WCOLS = BN / WAVES_N;
  constexpr int MF = WROWS / 16;
  constexpr int NF = WCOLS / 16;
  constexpr int HOWO = HO*WO;
  __shared__ unsigned short As[BM*BK];
  __shared__ unsigned short Bs[BN*BK];
  const int tid = threadIdx.x;
  const int bm = blockIdx.x * BM;
  const int bn = blockIdx.y * BN;
  const int lane = tid & 63, w = tid >> 6;
  const int wm = w / WAVES_N, wn = w % WAVES_N;
  const int m0 = wm * WROWS, n0 = wn * WCOLS;

  f32x4 acc[MF][NF] = {};

  const int ar = tid >> 1;
  const int as0 = 4 * (tid & 1);
  const int row_g = bm + ar;
  int a_n = 0, a_oy = 0, a_ox = 0;
  if (AMODE != 0){ a_n = row_g / HOWO; int p = row_g - a_n*HOWO; a_oy = p / WO; a_ox = p - a_oy*WO; }

  for (int kt = 0; kt < K; kt += BK){
    #pragma unroll
    for (int si = 0; si < 4; ++si){
      int s = as0 + si;
      int k0 = kt + s*8;
      u16x8 val;
      if constexpr (AMODE == 0){
        val = *(const u16x8*)((const unsigned short*)Av + (size_t)row_g*lda + k0);
      } else if constexpr (AMODE == 1){
        int ic = k0 >> 6, r = k0 & 63, ky = r >> 3;
        const float* src = (const float*)Av +
            (((size_t)(a_n*CIN + ic)*HI + a_oy*ST + ky)*WI + a_ox*ST);
        f32x4 f0 = *(const f32x4*)src;
        f32x4 f1 = *(const f32x4*)(src + 4);
        val[0]=f2bf(f0[0]); val[1]=f2bf(f0[1]); val[2]=f2bf(f0[2]); val[3]=f2bf(f0[3]);
        val[4]=f2bf(f1[0]); val[5]=f2bf(f1[1]); val[6]=f2bf(f1[2]); val[7]=f2bf(f1[3]);
      } else {
        int tap = k0 / CIN, ic0 = k0 - tap*CIN;
        int ky = tap / KW, kx = tap - ky*KW;
        const unsigned short* src = (const unsigned short*)Av +
            (((size_t)(a_n*HI + a_oy*ST + ky)*WI + a_ox*ST + kx)*CIN + ic0);
        val = *(const u16x8*)src;
      }
      int phys = s ^ ((ar >> 1) & 7);
      *(u16x8*)&As[ar*BK + phys*8] = val;
    }
    if constexpr (BN == 64){
      int br = tid >> 2, bs0 = 2*(tid & 3);
      #pragma unroll
      for (int si = 0; si < 2; ++si){
        int s = bs0 + si, k0 = kt + s*8;
        int n_g = bn + br;
        u16x8 val = {};
        if (!NGUARD || n_g < N) val = *(const u16x8*)(B + (size_t)n_g*K + k0);
        int phys = s ^ ((br >> 1) & 7);
        *(u16x8*)&Bs[br*BK + phys*8] = val;
      }
    } else {
      int br = tid >> 3, s = tid & 7, k0 = kt + s*8;
      int n_g = bn + br;
      u16x8 val = {};
      if (!NGUARD || n_g < N) val = *(const u16x8*)(B + (size_t)n_g*K + k0);
      int phys = s ^ ((br >> 1) & 7);
      *(u16x8*)&Bs[br*BK + phys*8] = val;
    }
    __syncthreads();
    #pragma unroll
    for (int ks = 0; ks < 2; ++ks){
      s16x8 a[MF], b[NF];
      #pragma unroll
      for (int i = 0; i < MF; ++i){
        int row = m0 + i*16 + (lane & 15);
        int phys = (ks*4 + (lane >> 4)) ^ ((row >> 1) & 7);
        a[i] = *(const s16x8*)&As[row*BK + phys*8];
      }
      #pragma unroll
      for (int j = 0; j < NF; ++j){
        int row = n0 + j*16 + (lane & 15);
        int phys = (ks*4 + (lane >> 4)) ^ ((row >> 1) & 7);
        b[j] = *(const s16x8*)&Bs[row*BK + phys*8];
      }
      #pragma unroll
      for (int i = 0; i < MF; ++i)
        #pragma unroll
        for (int j = 0; j < NF; ++j)
          acc[i][j] = __builtin_amdgcn_mfma_f32_16x16x32_bf16(a[i], b[j], acc[i][j], 0, 0, 0);
    }
    __syncthreads();
  }

  if constexpr (CMODE == 3){
    float* Cf = (float*)Cv;
    #pragma unroll
    for (int i = 0; i < MF; ++i)
      #pragma unroll
      for (int j = 0; j < NF; ++j){
        int col = bn + n0 + j*16 + (lane & 15);
        float bv = (bias && (!NGUARD || col < N)) ? bias[col] : 0.f;
        #pragma unroll
        for (int q = 0; q < 4; ++q){
          int row = bm + m0 + i*16 + (lane >> 4)*4 + q;
          float v = acc[i][j][q] + bv;
          if (RELU) v = fmaxf(v, 0.f);
          if (!NGUARD || col < N) Cf[(size_t)row*ldc + col] = v;
        }
      }
  } else {
    unsigned short* tile = As;
    #pragma unroll
    for (int i = 0; i < MF; ++i)
      #pragma unroll
      for (int j = 0; j < NF; ++j){
        int col = n0 + j*16 + (lane & 15);
        float bv = bias ? bias[bn + col] : 0.f;
        #pragma unroll
        for (int q = 0; q < 4; ++q){
          int row = m0 + i*16 + (lane >> 4)*4 + q;
          float v = acc[i][j][q] + bv;
          if (RELU) v = fmaxf(v, 0.f);
          tile[row*BN + col] = f2bf(v);
        }
      }
    __syncthreads();
    unsigned short* Cu = (unsigned short*)Cv;
    constexpr int CHUNKS = (BM*BN)/(256*8);
    #pragma unroll
    for (int c = 0; c < CHUNKS; ++c){
      int flat = tid*8 + c*2048;
      int row = flat / BN, col = flat - (flat/BN)*BN;
      u16x8 v = *(const u16x8*)&tile[flat];
      int rg = bm + row;
      size_t addr;
      if constexpr (CMODE == 0) addr = (size_t)rg*ldc + bn + col;
      else { int n = rg >> 4, p = rg & 15; addr = (size_t)n*cstride + p*64 + col; }
      *(u16x8*)&Cu[addr] = v;
    }
  }
}

// ---------------------------------------------------------------------------
// LSTM: one block per segment; both stacks. 256 threads (4 waves).
// e = tid>>1 (element, <100 active), sub = tid&1.
// sub0 owns full gate rows i(e), g(e); sub1 owns f(e), o(e) -- 100 packed
// f16-pair weight u32 per thread, full 50-pair dots in-register.
// h: 50 packed u32 in LDS, read as 13 broadcast ds_read_b128 per wave.
// sub0 sends i*g via shfl_xor(1); sub1 holds c in a register, computes h,
// writes it to the double-buffered h (read t&1, write (t+1)&1): 1 barrier.
// L1a: batch x-part into LDS Xl1 (same-thread write/read, no barriers).
// Head fused.
// ---------------------------------------------------------------------------
__global__ __launch_bounds__(256,1) void lstm_k(
    const float* __restrict__ X0s, const float* __restrict__ X0r,
    const unsigned int* __restrict__ wpk,  // 6 x [50][400] u32 packed f16 pairs
    const float* __restrict__ s_bih0, const float* __restrict__ s_bhh0,
    const float* __restrict__ s_bih1, const float* __restrict__ s_bhh1,
    const float* __restrict__ r_bih0, const float* __restrict__ r_bhh0,
    const float* __restrict__ r_bih1, const float* __restrict__ r_bhh1,
    const float* __restrict__ f1w, const float* __restrict__ f1b,
    const float* __restrict__ f2w, const float* __restrict__ f2b,
    float* __restrict__ out)
{
  __shared__ alignas(16) unsigned int h0p[2][56];   // dbuf, 50 pairs (+pad)
  __shared__ alignas(16) unsigned int h1p[2][56];
  __shared__ alignas(16) unsigned int hbufp[1792];  // 32 steps x 56 pairs
  __shared__ alignas(16) float Xl1[12800];          // layer-1 x-part, 32 x 400
  __shared__ float xin[200];                        // head input [outR|outS]
  __shared__ float mid[512];                        // head hidden

  const int b = blockIdx.x, tid = threadIdx.x;
  const int e = tid >> 1, sub = tid & 1;
  const bool act = (e < 100);
  const int eS = act ? e : 0;            // clamped for safe addressing
  const int gA = sub*100 + eS;           // sub0: i-gate, sub1: f-gate
  const int gB = gA + 200;               // sub0: g-gate, sub1: o-gate

  if (tid < 56){ h0p[0][tid]=0u; h0p[1][tid]=0u; h1p[0][tid]=0u; h1p[1][tid]=0u; }
  for (int q = tid; q < 1792; q += 256) hbufp[q] = 0u;
  float c0r = 0.f, c1r = 0.f;
  __syncthreads();

  #pragma unroll 1
  for (int s = 0; s < 2; ++s){
    const float* Xp = (s ? X0r : X0s) + (size_t)b*32*400;
    const unsigned int* w0P  = wpk + (size_t)(s ? 3 : 0)*20000;
    const unsigned int* w1xP = wpk + (size_t)(s ? 4 : 1)*20000;
    const unsigned int* w1hP = wpk + (size_t)(s ? 5 : 2)*20000;
    const float* bi0 = s ? r_bih0 : s_bih0;
    const float* bh0 = s ? r_bhh0 : s_bhh0;
    const float* bi1 = s ? r_bih1 : s_bih1;
    const float* bh1 = s ? r_bhh1 : s_bhh1;

    // ------------- layer 0 (recurrent; 1 barrier/step) -------------
    {
      unsigned int wA[50], wB[50];
      #pragma unroll
      for (int p = 0; p < 50; ++p){
        wA[p] = w0P[p*400 + gA];
        wB[p] = w0P[p*400 + gB];
      }
      float bsA = bi0[gA] + bh0[gA];
      float bsB = bi0[gB] + bh0[gB];
      float xcA = Xp[gA], xcB = Xp[gB], xnA, xnB;
      #pragma unroll 1
      for (int t = 0; t < 32; ++t){
        if (t < 31){ xnA = Xp[(t+1)*400 + gA]; xnB = Xp[(t+1)*400 + gB]; }
        const u32x4* h4 = (const u32x4*)h0p[t & 1];
        float a0=0.f, a1=0.f, b0=0.f, b1=0.f;
        #pragma unroll
        for (int i = 0; i < 12; ++i){
          u32x4 hv = h4[i];
          a0 = dot2h(wA[4*i+0], hv[0], a0);
          a1 = dot2h(wA[4*i+1], hv[1], a1);
          a0 = dot2h(wA[4*i+2], hv[2], a0);
          a1 = dot2h(wA[4*i+3], hv[3], a1);
          b0 = dot2h(wB[4*i+0], hv[0], b0);
          b1 = dot2h(wB[4*i+1], hv[1], b1);
          b0 = dot2h(wB[4*i+2], hv[2], b0);
          b1 = dot2h(wB[4*i+3], hv[3], b1);
        }
        { u32x4 hv = h4[12];
          a0 = dot2h(wA[48], hv[0], a0);
          a1 = dot2h(wA[49], hv[1], a1);
          b0 = dot2h(wB[48], hv[0], b0);
          b1 = dot2h(wB[49], hv[1], b1);
        }
        float preA = (a0 + a1) + xcA + bsA;
        float preB = (b0 + b1) + xcB + bsB;
        float vA = sigmoidf_(preA);                       // i (sub0) / f (sub1)
        float vB = sub ? sigmoidf_(preB) : tanhf_(preB);  // o (sub1) / g (sub0)
        float send = vA * vB;                             // sub0: i*g
        float recv = __shfl_xor(send, 1);
        if (act && sub){
          c0r = vA*c0r + recv;
          float hn = vB * tanhf_(c0r);
          unsigned short hv16 = f2h(hn);
          ((unsigned short*)h0p[(t+1) & 1])[e] = hv16;
          ((unsigned short*)hbufp)[t*112 + e] = hv16;
        }
        xcA = xnA; xcB = xnB;
        __syncthreads();
      }
    }
    // ------- layer 1a: x-part pre-acts (batch; same-thread LDS, no barrier) -------
    {
      unsigned int wA[50], wB[50];
      #pragma unroll
      for (int p = 0; p < 50; ++p){
        wA[p] = w1xP[p*400 + gA];
        wB[p] = w1xP[p*400 + gB];
      }
      float bsA = bi1[gA] + bh1[gA];
      float bsB = bi1[gB] + bh1[gB];
      #pragma unroll 1
      for (int t = 0; t < 32; ++t){
        const u32x4* x4 = (const u32x4*)&hbufp[t*56];
        float a0=0.f, a1=0.f, b0=0.f, b1=0.f;
        #pragma unroll
        for (int i = 0; i < 12; ++i){
          u32x4 hv = x4[i];
          a0 = dot2h(wA[4*i+0], hv[0], a0);
          a1 = dot2h(wA[4*i+1], hv[1], a1);
          a0 = dot2h(wA[4*i+2], hv[2], a0);
          a1 = dot2h(wA[4*i+3], hv[3], a1);
          b0 = dot2h(wB[4*i+0], hv[0], b0);
          b1 = dot2h(wB[4*i+1], hv[1], b1);
          b0 = dot2h(wB[4*i+2], hv[2], b0);
          b1 = dot2h(wB[4*i+3], hv[3], b1);
        }
        { u32x4 hv = x4[12];
          a0 = dot2h(wA[48], hv[0], a0);
          a1 = dot2h(wA[49], hv[1], a1);
          b0 = dot2h(wB[48], hv[0], b0);
          b1 = dot2h(wB[49], hv[1], b1);
        }
        if (act){
          Xl1[t*400 + gA] = (a0 + a1) + bsA;
          Xl1[t*400 + gB] = (b0 + b1) + bsB;
        }
      }
    }
    // ------------- layer 1b: recurrent (1 barrier/step) -------------
    {
      unsigned int wA[50], wB[50];
      #pragma unroll
      for (int p = 0; p < 50; ++p){
        wA[p] = w1hP[p*400 + gA];
        wB[p] = w1hP[p*400 + gB];
      }
      #pragma unroll 1
      for (int t = 0; t < 32; ++t){
        const u32x4* h4 = (const u32x4*)h1p[t & 1];
        float a0=0.f, a1=0.f, b0=0.f, b1=0.f;
        #pragma unroll
        for (int i = 0; i < 12; ++i){
          u32x4 hv = h4[i];
          a0 = dot2h(wA[4*i+0], hv[0], a0);
          a1 = dot2h(wA[4*i+1], hv[1], a1);
          a0 = dot2h(wA[4*i+2], hv[2], a0);
          a1 = dot2h(wA[4*i+3], hv[3], a1);
          b0 = dot2h(wB[4*i+0], hv[0], b0);
          b1 = dot2h(wB[4*i+1], hv[1], b1);
          b0 = dot2h(wB[4*i+2], hv[2], b0);
          b1 = dot2h(wB[4*i+3], hv[3], b1);
        }
        { u32x4 hv = h4[12];
          a0 = dot2h(wA[48], hv[0], a0);
          a1 = dot2h(wA[49], hv[1], a1);
          b0 = dot2h(wB[48], hv[0], b0);
          b1 = dot2h(wB[49], hv[1], b1);
        }
        float preA = (a0 + a1) + Xl1[t*400 + gA];
        float preB = (b0 + b1) + Xl1[t*400 + gB];
        float vA = sigmoidf_(preA);
        float vB = sub ? sigmoidf_(preB) : tanhf_(preB);
        float send = vA * vB;
        float recv = __shfl_xor(send, 1);
        if (act && sub){
          c1r = vA*c1r + recv;
          float hn = vB * tanhf_(c1r);
          ((unsigned short*)h1p[(t+1) & 1])[e] = f2h(hn);
          if (t == 31){
            if (s) xin[e] = hn;          // outR -> head cols [0,100)
            else   xin[100 + e] = hn;    // outS -> head cols [100,200)
          }
        }
        __syncthreads();
      }
    }
  }

  // ------------- fused head: out[b] = relu(xin@f1w^T+b1)@f2w^T+b2 -------------
  for (int r = tid; r < 512; r += 256){
    float acc = f1b[r];
    const float* wrow = f1w + (size_t)r*200;
    #pragma unroll 4
    for (int k = 0; k < 200; ++k) acc += xin[k]*wrow[k];
    mid[r] = fmaxf(acc, 0.f);
  }
  __syncthreads();
  if (tid < 130){
    float acc = f2b[tid];
    const float* wrow = f2w + (size_t)tid*512;
    #pragma unroll 4
    for (int k = 0; k < 512; ++k) acc += mid[k]*wrow[k];
    out[b*130 + tid] = acc;
  }
}

extern "C" void kernel_launch(void* const* d_in, const int* in_sizes, int n_in,
                              void* d_out, int out_size, void* d_ws, size_t ws_size,
                              hipStream_t stream)
{
  const float* obs  = (const float*)d_in[0];
  const float* data = (const float*)d_in[1];
  const float* c1w = (const float*)d_in[2];  const float* c1b = (const float*)d_in[3];
  const float* c2w = (const float*)d_in[4];  const float* c2b = (const float*)d_in[5];
  const float* c3w = (const float*)d_in[6];  const float* c3b = (const float*)d_in[7];
  const float* l1w = (const float*)d_in[8];  const float* l1b = (const float*)d_in[9];
  const float* l2w = (const float*)d_in[10]; const float* l2b = (const float*)d_in[11];
  const float* s_wih0=(const float*)d_in[12]; const float* s_whh0=(const float*)d_in[13];
  const float* s_bih0=(const float*)d_in[14]; const float* s_bhh0=(const float*)d_in[15];
  const float* s_wih1=(const float*)d_in[16]; const float* s_whh1=(const float*)d_in[17];
  const float* s_bih1=(const float*)d_in[18]; const float* s_bhh1=(const float*)d_in[19];
  const float* r_wih0=(const float*)d_in[20]; const float* r_whh0=(const float*)d_in[21];
  const float* r_bih0=(const float*)d_in[22]; const float* r_bhh0=(const float*)d_in[23];
  const float* r_wih1=(const float*)d_in[24]; const float* r_whh1=(const float*)d_in[25];
  const float* r_bih1=(const float*)d_in[26]; const float* r_bhh1=(const float*)d_in[27];
  const float* f1w=(const float*)d_in[28]; const float* f1b=(const float*)d_in[29];
  const float* f2w=(const float*)d_in[30]; const float* f2b=(const float*)d_in[31];
  float* out = (float*)d_out;
  (void)in_sizes; (void)n_in; (void)out_size;

  // ---- workspace layout (bytes, 256-aligned); total ~ 67 MB ----
  char* p = (char*)d_ws;
  auto alloc = [&](size_t bytes){ void* r = (void*)p; p += (bytes + 255) & ~(size_t)255; return r; };
  unsigned short* data_bf = (unsigned short*)alloc((size_t)2048*1536*2);
  unsigned short* c1w_bf  = (unsigned short*)alloc((size_t)32*192*2);
  unsigned short* c2w_bf  = (unsigned short*)alloc((size_t)64*512*2);
  unsigned short* c3w_bf  = (unsigned short*)alloc((size_t)64*576*2);
  unsigned short* l1w_bf  = (unsigned short*)alloc((size_t)1024*1536*2);
  unsigned short* l2w_bf  = (unsigned short*)alloc((size_t)512*1024*2);
  unsigned short* wihS_bf = (unsigned short*)alloc((size_t)400*1536*2);
  unsigned short* wihR_bf = (unsigned short*)alloc((size_t)400*1536*2);
  unsigned short* conv1o  = (unsigned short*)alloc((size_t)2048*225*32*2);  // NHWC
  unsigned short* conv2o  = (unsigned short*)alloc((size_t)2048*36*64*2);   // NHWC
  unsigned short* feat    = (unsigned short*)alloc((size_t)2048*1536*2);
  unsigned short* lin1o   = (unsigned short*)alloc((size_t)2048*1024*2);
  float* X0s  = (float*)alloc((size_t)1024*400*4);
  float* X0r  = (float*)alloc((size_t)1024*400*4);
  unsigned int* wpk = (unsigned int*)alloc((size_t)6*20000*4);
  (void)ws_size;

  // ---- merged prep (1 launch) ----
  prep_k<<<dim3(512,9),256,0,stream>>>(
      data, data_bf, l1w, l1w_bf, l2w, l2w_bf, c1w, c1w_bf,
      c2w, c2w_bf, c3w, c3w_bf, s_wih0, wihS_bf, r_wih0, wihR_bf,
      s_whh0, s_wih1, s_whh1, r_whh0, r_wih1, r_whh1, wpk);

  // ---- GEMM chain (bf16 MFMA, fp32 accumulate) ----
  mgemm<128,32,4,1, 1,0,1,0, 3,64,64,8,8,4,15,15><<<dim3(3600,1),256,0,stream>>>(
      obs, c1w_bf, conv1o, c1b, 460800, 32, 192, 0, 32, 0);
  mgemm<128,64,2,2, 2,0,1,0, 32,15,15,4,4,2,6,6><<<dim3(576,1),256,0,stream>>>(
      conv1o, c2w_bf, conv2o, c2b, 73728, 64, 512, 0, 64, 0);
  mgemm<128,64,2,2, 0,0,1,0, 1,1,1,1,1,1,1,1><<<dim3(16,16),256,0,stream>>>(
      data_bf, l1w_bf, lin1o, l1b, 2048, 1024, 1536, 1536, 1024, 0);
  mgemm<128,64,2,2, 2,2,1,0, 64,6,6,3,3,1,4,4><<<dim3(256,1),256,0,stream>>>(
      conv2o, c3w_bf, feat, c3b, 32768, 64, 576, 0, 0, 1536);
  mgemm<128,64,2,2, 0,0,0,0, 1,1,1,1,1,1,1,1><<<dim3(16,8),256,0,stream>>>(
      lin1o, l2w_bf, feat + 1024, l2b, 2048, 512, 1024, 1024, 1536, 0);
  mgemm<128,64,2,2, 0,3,0,1, 1,1,1,1,1,1,1,1><<<dim3(8,7),256,0,stream>>>(
      feat, wihS_bf, X0s, (const float*)nullptr, 1024, 400, 1536, 1536, 400, 0);
  mgemm<128,64,2,2, 0,3,0,1, 1,1,1,1,1,1,1,1><<<dim3(8,7),256,0,stream>>>(
      feat + (size_t)1024*1536, wihR_bf, X0r, (const float*)nullptr, 1024, 400, 1536, 1536, 400, 0);

  // ---- sequential LSTM + fused head ----
  lstm_k<<<32,256,0,stream>>>(X0s, X0r, wpk,
                              s_bih0,s_bhh0,s_bih1,s_bhh1,
                              r_bih0,r_bhh0,r_bih1,r_bhh1,
                              f1w, f1b, f2w, f2b, out);
}